// Round 1
// 73.313 us; speedup vs baseline: 1.0219x; 1.0219x over previous
//
#include <hip/hip_runtime.h>
#include <math.h>

// Problem constants (fixed by setup_inputs in the reference)
#define HH   512
#define NST  32
#define MM   2
#define LL   2048
#define NS   (MM * NST)   // 64 fractional states per h
#define TL   8            // l per thread; 256 threads * 8 = 2048 = L

// K[h,l] = 2*Re( sum_s C_disc[h,s] * w_s^l ),  w = exp(dtA)
//
// r_s(l) = Re(Cc_s * w_s^l) obeys the exactly-stable 2nd-order recurrence
//   r(l+1) = p*r(l) + q*r(l-1),  p = 2*Re(w), q = -|w|^2
// -> 3 VALU slots per (state,l) and ZERO transcendentals in the main loop.
// Chunk-start values come from factored LDS power tables:
//   l0 = 8*tid, tid = 16*qi + ri  =>  w^l0 = (w^128)^qi * (w^8)^ri
//   T1[s][ri] = {Re,Im(w^(8ri)), Re,Im(w^(8ri+1))}
//   T2[s][qi] = {Re,Im(Cc*(w^128)^qi), p, q}
//
// This version:
//  * tables are column-XOR-swizzled (entry e at col e^(s&15)): preamble
//    ds_write_b128 was a 64-lane -> 4-bank pileup (bank=4e lane-invariant),
//    now 8 words/bank (conflict-free); hot-loop reads keep the 2-way-merged
//    full-row spread (16 distinct cols per row).
//  * table build is 4-way wave-parallel (T1 lo/hi via w^64 jump-in, T2 lo/hi
//    via w^1024 jump-in) instead of one wave running two 16-step chains.
//  * the 4-state LDS group loads are double-buffered (ping-pong A/B) so the
//    ~120cy LDS latency hides under the previous group's ~190cy of FMA work
//    (only 2 waves/SIMD are resident -> ILP must cover latency).
__global__ __launch_bounds__(256) void loong_kernel(
    const float* __restrict__ C_real,      // [1, H, NST, 2]
    const float* __restrict__ log_dt,      // [H]
    const float* __restrict__ log_A_real,  // [H, NST]
    const float* __restrict__ A_imag,      // [H, NST]
    const float* __restrict__ omega_logit, // [M]
    const float* __restrict__ eta_logit,   // [M]
    float* __restrict__ out)               // [1, H, L]
{
    __shared__ float4 sT1[NS][16];
    __shared__ float4 sT2[NS][16];

    const int h   = blockIdx.x;
    const int tid = threadIdx.x;

    // ---- Preamble: 256 threads, 4 per state (part = wave index) ----
    {
        const int s    = tid & (NS - 1);
        const int part = tid >> 6;          // 0..3, wave-uniform
        const int m = s >> 5;
        const int n = s & 31;
        const float dt  = expf(log_dt[h]);
        const float Are = -expf(log_A_real[h * NST + n]);
        const float Aim = A_imag[h * NST + n];
        const float om = 1e-6f + (100.0f - 1e-6f) / (1.0f + expf(-omega_logit[m]));
        const float et = 1e-6f + (10.0f  - 1e-6f) / (1.0f + expf(-eta_logit[m]));
        const float Afr = fmaf(et, Are, -om);
        const float Afi = et * Aim;
        const float Cfr = et * C_real[(h * NST + n) * 2 + 0];
        const float Cfi = et * C_real[(h * NST + n) * 2 + 1];
        const float ar = dt * Afr, ai = dt * Afi;       // dtA
        const float e = expf(ar);
        float sn, cs;
        sincosf(ai, &sn, &cs);                          // |ai| <= ~10, accurate
        const float Er = e * cs, Ei = e * sn;           // w = exp(dtA)
        // C_disc = C_frac * (exp(dtA)-1) / (A_frac + 1e-8)
        const float dr = Afr + 1e-8f, di = Afi;
        const float inv = 1.0f / fmaf(dr, dr, di * di);
        const float numr = Er - 1.0f, numi = Ei;
        const float fr = fmaf(numr, dr,  numi * di) * inv;
        const float fi = fmaf(numi, dr, -numr * di) * inv;
        float Cdr = fmaf(Cfr, fr, -(Cfi * fi));
        float Cdi = fmaf(Cfr, fi,  (Cfi * fr));
        if (sqrtf(fmaf(Afr, Afr, Afi * Afi)) < 1e-6f) { // small-|A| branch
            Cdr = Cfr * dt;
            Cdi = Cfi * dt;
        }
        const float Ccr = 2.0f * Cdr, Cci = 2.0f * Cdi; // fold the 2*Re factor
        const float p  = 2.0f * Er;
        const float qc = -fmaf(Er, Er, Ei * Ei);

        // powers of w by repeated squaring: w2..w8..w64..w128..w1024
        const float w2r = fmaf(Er, Er, -(Ei * Ei)),     w2i = 2.0f * Er * Ei;
        const float w4r = fmaf(w2r, w2r, -(w2i * w2i)), w4i = 2.0f * w2r * w2i;
        const float w8r = fmaf(w4r, w4r, -(w4i * w4i)), w8i = 2.0f * w4r * w4i;
        const float w16r  = fmaf(w8r,  w8r,  -(w8i  * w8i)),  w16i  = 2.0f * w8r  * w8i;
        const float w32r  = fmaf(w16r, w16r, -(w16i * w16i)), w32i  = 2.0f * w16r * w16i;
        const float w64r  = fmaf(w32r, w32r, -(w32i * w32i)), w64i  = 2.0f * w32r * w32i;
        const float w128r = fmaf(w64r, w64r, -(w64i * w64i)), w128i = 2.0f * w64r * w64i;
        const float w256r  = fmaf(w128r, w128r, -(w128i * w128i)), w256i  = 2.0f * w128r * w128i;
        const float w512r  = fmaf(w256r, w256r, -(w256i * w256i)), w512i  = 2.0f * w256r * w256i;
        const float w1024r = fmaf(w512r, w512r, -(w512i * w512i)), w1024i = 2.0f * w512r * w512i;

        if (part < 2) {
            // T1 entries [8*part .. 8*part+7]: u = (w^8)^e, also u*w
            float ur = 1.0f, ui = 0.0f;
            if (part == 1) { ur = w64r; ui = w64i; }    // jump-in at w^64
            const int base = part << 3;
#pragma unroll
            for (int r = 0; r < 8; ++r) {
                const int e = base + r;
                sT1[s][e ^ (s & 15)] = make_float4(ur, ui,
                                                   fmaf(ur, Er, -(ui * Ei)),
                                                   fmaf(ur, Ei,  (ui * Er)));
                const float nr = fmaf(ur, w8r, -(ui * w8i));
                const float ni = fmaf(ur, w8i,  (ui * w8r));
                ur = nr; ui = ni;
            }
        } else {
            // T2 entries [8*(part&1) .. +7]: v = Cc*(w^128)^e ; pack {p,q}
            float vr = Ccr, vi = Cci;
            if (part == 3) {                            // jump-in at Cc*w^1024
                const float tr = fmaf(vr, w1024r, -(vi * w1024i));
                const float ti = fmaf(vr, w1024i,  (vi * w1024r));
                vr = tr; vi = ti;
            }
            const int base = (part & 1) << 3;
#pragma unroll
            for (int q = 0; q < 8; ++q) {
                const int e = base + q;
                sT2[s][e ^ (s & 15)] = make_float4(vr, vi, p, qc);
                const float nr = fmaf(vr, w128r, -(vi * w128i));
                const float ni = fmaf(vr, w128i,  (vi * w128r));
                vr = nr; vi = ni;
            }
        }
    }
    __syncthreads();

    const int ri = tid & 15;
    const int qi = tid >> 4;

    float acc[TL];
#pragma unroll
    for (int j = 0; j < TL; ++j) acc[j] = 0.0f;

    float4 A1[4], A2[4], B1[4], B2[4];

#define LOADG(T1v, T2v, S0)                                            \
    _Pragma("unroll")                                                  \
    for (int u = 0; u < 4; ++u) {                                      \
        const int ss = (S0) + u;                                       \
        T1v[u] = sT1[ss][ri ^ (ss & 15)];                              \
        T2v[u] = sT2[ss][qi ^ (ss & 15)];                              \
    }

#define COMPG(T1v, T2v)                                                \
    _Pragma("unroll")                                                  \
    for (int u = 0; u < 4; ++u) {                                      \
        const float pp = T2v[u].z, qq = T2v[u].w;                      \
        float r0 = fmaf(T1v[u].x, T2v[u].x, -(T1v[u].y * T2v[u].y));   \
        float r1 = fmaf(T1v[u].z, T2v[u].x, -(T1v[u].w * T2v[u].y));   \
        acc[0] += r0;                                                  \
        acc[1] += r1;                                                  \
        _Pragma("unroll")                                              \
        for (int j = 2; j < TL; ++j) {                                 \
            const float rn = fmaf(pp, r1, qq * r0);                    \
            acc[j] += rn;                                              \
            r0 = r1; r1 = rn;                                          \
        }                                                              \
    }

    // ping-pong pipeline over 16 groups of 4 states: load one group ahead
    LOADG(A1, A2, 0)
#pragma unroll
    for (int g = 0; g < 7; ++g) {
        LOADG(B1, B2, 8 * g + 4)
        COMPG(A1, A2)
        LOADG(A1, A2, 8 * g + 8)
        COMPG(B1, B2)
    }
    LOADG(B1, B2, 60)
    COMPG(A1, A2)
    COMPG(B1, B2)

#undef LOADG
#undef COMPG

    float4* o = reinterpret_cast<float4*>(out + (size_t)h * LL + (size_t)tid * TL);
    o[0] = make_float4(acc[0], acc[1], acc[2], acc[3]);
    o[1] = make_float4(acc[4], acc[5], acc[6], acc[7]);
}

extern "C" void kernel_launch(void* const* d_in, const int* in_sizes, int n_in,
                              void* d_out, int out_size, void* d_ws, size_t ws_size,
                              hipStream_t stream) {
    const float* C_real      = (const float*)d_in[0];
    const float* log_dt      = (const float*)d_in[1];
    const float* log_A_real  = (const float*)d_in[2];
    const float* A_imag      = (const float*)d_in[3];
    const float* omega_logit = (const float*)d_in[4];
    const float* eta_logit   = (const float*)d_in[5];
    float* out = (float*)d_out;

    loong_kernel<<<dim3(HH), dim3(256), 0, stream>>>(
        C_real, log_dt, log_A_real, A_imag, omega_logit, eta_logit, out);
}